// Round 6
// baseline (219.854 us; speedup 1.0000x reference)
//
#include <hip/hip_runtime.h>
#include <hip/hip_bf16.h>

#define NI 768
#define NJ 768
#define CN 512
#define CP 128
#define NH 8
#define CH 32
#define HC 256   // NH*CH
#define NSTRIP 12   // NJ/64

typedef float  fx4  __attribute__((ext_vector_type(4)));
typedef float  fx2  __attribute__((ext_vector_type(2)));
typedef short  bv8  __attribute__((ext_vector_type(8)));

__device__ __forceinline__ short f2bf(float f) {
    __hip_bfloat16 h = __float2bfloat16(f);
    return *reinterpret_cast<short*>(&h);
}
__device__ __forceinline__ float bf2f(unsigned short u) {
    union { unsigned int u; float f; } c; c.u = ((unsigned int)u) << 16; return c.f;
}

// ---------------------------------------------------------------- node kernel
// blocks [0,96):   i-side: LN(node_i) -> qx(f32), qs(f32, scaled), gs(f32)
// blocks [96,192): j-side: LN(node_j) -> ksf(f32), vtb(bf16 transposed [HC][NJ])
__global__ __launch_bounds__(256) void node_kernel(
    const float* __restrict__ node_i, const float* __restrict__ node_j,
    const float* __restrict__ ln_i_w, const float* __restrict__ ln_i_b,
    const float* __restrict__ ln_j_w, const float* __restrict__ ln_j_b,
    const float* __restrict__ Wq, const float* __restrict__ Wk,
    const float* __restrict__ Wv, const float* __restrict__ Wg,
    const float* __restrict__ bg,
    float* __restrict__ qx, float* __restrict__ qs,
    float* __restrict__ ksf, unsigned short* __restrict__ vtb,
    float* __restrict__ gs)
{
    __shared__ float xs[8][CN];
    __shared__ float red[4][8][2];
    const int bid = blockIdx.x;
    const int t = threadIdx.x;
    const bool isj = bid >= 96;
    const int r0 = (isj ? bid - 96 : bid) * 8;
    const float* xin = isj ? node_j : node_i;
    const float* lw = isj ? ln_j_w : ln_i_w;
    const float* lb = isj ? ln_j_b : ln_i_b;
    const int wv = t >> 6;

    fx2 vrow[8]; float s8[8], q8[8];
#pragma unroll
    for (int r = 0; r < 8; ++r) {
        vrow[r] = *(const fx2*)(xin + (size_t)(r0 + r) * CN + t * 2);
        s8[r] = vrow[r][0] + vrow[r][1];
        q8[r] = vrow[r][0] * vrow[r][0] + vrow[r][1] * vrow[r][1];
    }
#pragma unroll
    for (int d = 1; d < 64; d <<= 1)
#pragma unroll
        for (int r = 0; r < 8; ++r) {
            s8[r] += __shfl_xor(s8[r], d);
            q8[r] += __shfl_xor(q8[r], d);
        }
    if ((t & 63) == 0)
#pragma unroll
        for (int r = 0; r < 8; ++r) { red[wv][r][0] = s8[r]; red[wv][r][1] = q8[r]; }
    __syncthreads();
    fx2 lwv = *(const fx2*)(lw + t * 2), lbv = *(const fx2*)(lb + t * 2);
#pragma unroll
    for (int r = 0; r < 8; ++r) {
        float s = red[0][r][0] + red[1][r][0] + red[2][r][0] + red[3][r][0];
        float q = red[0][r][1] + red[1][r][1] + red[2][r][1] + red[3][r][1];
        float mean = s * (1.f / CN);
        float var = q * (1.f / CN) - mean * mean;
        float rs = rsqrtf(var + 1e-5f);
        fx2 o;
        o[0] = (vrow[r][0] - mean) * rs * lwv[0] + lbv[0];
        o[1] = (vrow[r][1] - mean) * rs * lwv[1] + lbv[1];
        xs[r][t * 2] = o[0]; xs[r][t * 2 + 1] = o[1];
        if (!isj) *(fx2*)(qx + (size_t)(r0 + r) * CN + t * 2) = o;
    }
    __syncthreads();

    for (int m = 0; m < 2; ++m) {
        const float* W = isj ? (m ? Wv : Wk) : (m ? Wg : Wq);
        float acc[8] = {0.f,0.f,0.f,0.f,0.f,0.f,0.f,0.f};
        for (int cc = 0; cc < CN; cc += 4) {
            fx4 xv[8];
#pragma unroll
            for (int r = 0; r < 8; ++r) xv[r] = *(const fx4*)&xs[r][cc];
#pragma unroll
            for (int u = 0; u < 4; ++u) {
                float w = W[(size_t)(cc + u) * HC + t];
#pragma unroll
                for (int r = 0; r < 8; ++r) acc[r] = fmaf(xv[r][u], w, acc[r]);
            }
        }
        if (!isj) {
            if (m == 0) {
#pragma unroll
                for (int r = 0; r < 8; ++r)
                    qs[(size_t)(r0 + r) * HC + t] = acc[r] * 0.17677669529663687f;
            } else {
#pragma unroll
                for (int r = 0; r < 8; ++r)
                    gs[(size_t)(r0 + r) * HC + t] =
                        1.f / (1.f + __expf(-(acc[r] + bg[t])));
            }
        } else {
            if (m == 0) {
#pragma unroll
                for (int r = 0; r < 8; ++r)
                    ksf[(size_t)(r0 + r) * HC + t] = acc[r];
            } else {
                bv8 vv;
#pragma unroll
                for (int r = 0; r < 8; ++r) vv[r] = f2bf(acc[r]);
                *(bv8*)&vtb[(size_t)t * NJ + r0] = vv;   // transposed [HC][NJ]
            }
        }
    }
}

// ---------------------------------------------------------------- flash pair kernel
// One block = one i x 64 j strip. Pair loads + q row + mask issued FIRST
// (hidden under the in-LDS weight rebuild). Pair-bias via MFMA -> sb (LDS,
// f32, never hits HBM). Then QK (f32 VALU vs L2-hot K), exp (no max-sub,
// masked -> exp(-1e9)=0), strip denominator, PV (vs L2-hot bf16 V^T).
// Writes only f32 partials pnum/pden.
__global__ __launch_bounds__(256) void flash_pair_kernel(
    const float* __restrict__ pair, const float* __restrict__ pmask,
    const float* __restrict__ lnpw, const float* __restrict__ lnpb,
    const float* __restrict__ Wpb, const float* __restrict__ bpb,
    const float* __restrict__ Wpg, const float* __restrict__ bpg,
    const float* __restrict__ qs, const float* __restrict__ ksf,
    const unsigned short* __restrict__ vtb,
    float* __restrict__ pnum, float* __restrict__ pden)
{
    __shared__ unsigned short wcatT[16][136];
    __shared__ float redS[16][16], redC[16][16];
    __shared__ float scalS[16], scalC[16];
    __shared__ float sb[8][68];       // bias tile, f32
    __shared__ float qrow[HC];
    __shared__ float pmbuf[64];
    __shared__ float pbuf[8][64];     // probs

    const int t = threadIdx.x;
    const int bid = blockIdx.x;
    const int i = bid / NSTRIP;
    const int strip = bid % NSTRIP;
    const int jt64 = strip * 64;
    const int lane = t & 63, wave = t >> 6;
    const int o = lane & 15, kq = lane >> 4;
    const int jt = jt64 + wave * 16;

    // ---- early loads (HBM pair stream in flight from cycle 0) ----
    const float* prow = pair + ((size_t)i * NJ + (jt + o)) * CP + kq * 8;
    fx4 x0[4], x1[4];
#pragma unroll
    for (int s = 0; s < 4; ++s) {
        x0[s] = *(const fx4*)(prow + s * 32);
        x1[s] = *(const fx4*)(prow + s * 32 + 4);
    }
    const float qld = qs[(size_t)i * HC + t];
    float pmld = 0.f;
    if (t < 64) pmld = pmask[(size_t)i * NJ + jt64 + t];

    // ---- weight rebuild in LDS (covers the load latency) ----
    {
        const int oo = t & 15, cg = t >> 4;
        float pS = 0.f, pC = 0.f;
#pragma unroll
        for (int e = 0; e < 8; ++e) {
            int c = cg * 8 + e;
            float w = (oo < 8) ? Wpb[c * 8 + oo] : Wpg[c * 8 + (oo - 8)];
            float wv = lnpw[c] * w;
            short b = f2bf(wv);
            wcatT[oo][c] = (unsigned short)b;
            pS += bf2f((unsigned short)b);
            pC += lnpb[c] * w;
        }
        redS[cg][oo] = pS; redC[cg][oo] = pC;
        qrow[t] = qld;
        if (t < 64) pmbuf[t] = pmld;
        __syncthreads();
        if (t < 16) {
            float s = 0.f, c2 = 0.f;
#pragma unroll
            for (int k = 0; k < 16; ++k) { s += redS[k][t]; c2 += redC[k][t]; }
            scalS[t] = s;
            scalC[t] = c2 + ((t < 8) ? bpb[t] : bpg[t - 8]);
        }
        __syncthreads();
    }

    // ---- pair-bias (MFMA, LN folded) ----
    bv8 bfrag[4];
#pragma unroll
    for (int s = 0; s < 4; ++s)
        bfrag[s] = *(const bv8*)&wcatT[o][s * 32 + kq * 8];
    const float spb = scalS[o];
    const float cpb = scalC[o];

    float sum = 0.f, ssq = 0.f;
    bv8 afrag[4];
#pragma unroll
    for (int s = 0; s < 4; ++s) {
#pragma unroll
        for (int u = 0; u < 4; ++u) {
            float a = x0[s][u], b = x1[s][u];
            sum += a + b;
            ssq = fmaf(a, a, ssq);
            ssq = fmaf(b, b, ssq);
            afrag[s][u]     = f2bf(a);
            afrag[s][u + 4] = f2bf(b);
        }
    }
    sum += __shfl_xor(sum, 16); ssq += __shfl_xor(ssq, 16);
    sum += __shfl_xor(sum, 32); ssq += __shfl_xor(ssq, 32);

    fx4 acc = {0.f, 0.f, 0.f, 0.f};
#pragma unroll
    for (int s = 0; s < 4; ++s)
        acc = __builtin_amdgcn_mfma_f32_16x16x32_bf16(afrag[s], bfrag[s], acc, 0, 0, 0);

#pragma unroll
    for (int r = 0; r < 4; ++r) {
        const int p = kq * 4 + r;
        float sp = __shfl(sum, p);
        float qp = __shfl(ssq, p);
        float mean = sp * (1.f / CP);
        float var  = qp * (1.f / CP) - mean * mean;
        float rstd = rsqrtf(var + 1e-5f);
        float pre  = rstd * (acc[r] - mean * spb) + cpb;
        float part = __shfl_xor(pre, 8);
        if (o < 8) {
            float sig = 1.f / (1.f + __expf(-part));
            int jloc = wave * 16 + p;
            sb[o][jloc] = pre * sig + (pmbuf[jloc] - 1.f) * 1.0e9f;
        }
    }
    __syncthreads();

    // ---- QK + exp + strip denominator ----
    const int h = t >> 5, jl = t & 31;
    fx4 qv[8];
#pragma unroll
    for (int u = 0; u < 8; ++u) qv[u] = *(const fx4*)&qrow[h * CH + u * 4];

    const float* kp0 = ksf + (size_t)(jt64 + jl) * HC + h * CH;
    const float* kp1 = kp0 + (size_t)32 * HC;
    float s0 = 0.f, s1 = 0.f;
#pragma unroll
    for (int u = 0; u < 8; ++u) {
        fx4 kv = *(const fx4*)(kp0 + u * 4);
        s0 += qv[u][0]*kv[0] + qv[u][1]*kv[1] + qv[u][2]*kv[2] + qv[u][3]*kv[3];
    }
#pragma unroll
    for (int u = 0; u < 8; ++u) {
        fx4 kv = *(const fx4*)(kp1 + u * 4);
        s1 += qv[u][0]*kv[0] + qv[u][1]*kv[1] + qv[u][2]*kv[2] + qv[u][3]*kv[3];
    }
    float p0 = __expf(s0 + sb[h][jl]);
    float p1 = __expf(s1 + sb[h][jl + 32]);
    pbuf[h][jl] = p0; pbuf[h][jl + 32] = p1;
    float pd = p0 + p1;
#pragma unroll
    for (int d = 1; d < 32; d <<= 1) pd += __shfl_xor(pd, d);
    if (jl == 0) pden[((size_t)i * NSTRIP + strip) * NH + h] = pd;
    __syncthreads();

    // ---- PV over the strip ----
    const int c = t & 31;
    float ov = 0.f;
    const unsigned short* vp = vtb + (size_t)(h * CH + c) * NJ + jt64;
#pragma unroll
    for (int jo = 0; jo < 8; ++jo) {
        bv8 vv = *(const bv8*)(vp + jo * 8);
        fx4 pa = *(const fx4*)&pbuf[h][jo * 8];
        fx4 pb2 = *(const fx4*)&pbuf[h][jo * 8 + 4];
        ov += pa[0]*bf2f((unsigned short)vv[0]) + pa[1]*bf2f((unsigned short)vv[1])
            + pa[2]*bf2f((unsigned short)vv[2]) + pa[3]*bf2f((unsigned short)vv[3])
            + pb2[0]*bf2f((unsigned short)vv[4]) + pb2[1]*bf2f((unsigned short)vv[5])
            + pb2[2]*bf2f((unsigned short)vv[6]) + pb2[3]*bf2f((unsigned short)vv[7]);
    }
    pnum[((size_t)i * NSTRIP + strip) * HC + t] = ov;
}

// ---------------------------------------------------------------- reduce + gate + output projection + residual
__global__ __launch_bounds__(256) void reduce_out_kernel(
    const float* __restrict__ pnum, const float* __restrict__ pden,
    const float* __restrict__ gs, const float* __restrict__ qx,
    const float* __restrict__ Wo, const float* __restrict__ bo,
    const float* __restrict__ mi, float* __restrict__ outp)
{
    __shared__ float ogl[2][HC];
    const int r0 = blockIdx.x * 2;
    const int t = threadIdx.x;
    const int h = t >> 5;
#pragma unroll
    for (int r = 0; r < 2; ++r) {
        const int i = r0 + r;
        float n = 0.f, d = 0.f;
#pragma unroll
        for (int s = 0; s < NSTRIP; ++s) {
            n += pnum[((size_t)i * NSTRIP + s) * HC + t];
            d += pden[((size_t)i * NSTRIP + s) * NH + h];
        }
        ogl[r][t] = n / d * gs[(size_t)i * HC + t];
    }
    __syncthreads();

    float acc[2][2] = {{0,0},{0,0}};
    for (int cc = 0; cc < HC; cc += 4) {
        fx4 xr0 = *(const fx4*)&ogl[0][cc];
        fx4 xr1 = *(const fx4*)&ogl[1][cc];
#pragma unroll
        for (int u = 0; u < 4; ++u) {
            float w0 = Wo[(size_t)(cc + u) * CN + t];
            float w1 = Wo[(size_t)(cc + u) * CN + 256 + t];
            acc[0][0] = fmaf(xr0[u], w0, acc[0][0]); acc[0][1] = fmaf(xr0[u], w1, acc[0][1]);
            acc[1][0] = fmaf(xr1[u], w0, acc[1][0]); acc[1][1] = fmaf(xr1[u], w1, acc[1][1]);
        }
    }
#pragma unroll
    for (int r = 0; r < 2; ++r) {
        float mk = mi[r0 + r];
        size_t base = (size_t)(r0 + r) * CN;
        outp[base + t]       = qx[base + t]       + (acc[r][0] + bo[t])       * mk;
        outp[base + 256 + t] = qx[base + 256 + t] + (acc[r][1] + bo[t + 256]) * mk;
    }
}

// ---------------------------------------------------------------- launch
extern "C" void kernel_launch(void* const* d_in, const int* in_sizes, int n_in,
                              void* d_out, int out_size, void* d_ws, size_t ws_size,
                              hipStream_t stream)
{
    const float* node_i = (const float*)d_in[0];
    const float* node_j = (const float*)d_in[1];
    const float* pair   = (const float*)d_in[2];
    const float* pmask  = (const float*)d_in[3];
    const float* nmask  = (const float*)d_in[4];
    const float* ln_i_w = (const float*)d_in[5];
    const float* ln_i_b = (const float*)d_in[6];
    const float* ln_j_w = (const float*)d_in[7];
    const float* ln_j_b = (const float*)d_in[8];
    const float* ln_p_w = (const float*)d_in[9];
    const float* ln_p_b = (const float*)d_in[10];
    const float* W_pb   = (const float*)d_in[11];
    const float* b_pb   = (const float*)d_in[12];
    const float* W_pg   = (const float*)d_in[13];
    const float* b_pg   = (const float*)d_in[14];
    const float* Wq     = (const float*)d_in[15];
    const float* Wk     = (const float*)d_in[16];
    const float* Wv     = (const float*)d_in[17];
    const float* Wg     = (const float*)d_in[18];
    const float* bg     = (const float*)d_in[19];
    const float* Wo     = (const float*)d_in[20];
    const float* bo     = (const float*)d_in[21];
    float* outp = (float*)d_out;

    float* fw = (float*)d_ws;
    float* qx   = fw;                             // [NI][CN]
    float* gs   = qx + (size_t)NI * CN;           // [NI][HC]
    float* qs   = gs + (size_t)NI * HC;           // [NI][HC]
    float* ksf  = qs + (size_t)NI * HC;           // [NJ][HC]
    float* pnum = ksf + (size_t)NJ * HC;          // [NI][12][HC]
    float* pden = pnum + (size_t)NI * NSTRIP * HC;// [NI][12][NH]
    unsigned short* vtb = (unsigned short*)(pden + (size_t)NI * NSTRIP * NH); // [HC][NJ]

    hipLaunchKernelGGL(node_kernel, dim3(192), dim3(256), 0, stream,
                       node_i, node_j, ln_i_w, ln_i_b, ln_j_w, ln_j_b,
                       Wq, Wk, Wv, Wg, bg,
                       qx, qs, ksf, vtb, gs);
    hipLaunchKernelGGL(flash_pair_kernel, dim3(NI * NSTRIP), dim3(256), 0, stream,
                       pair, pmask,
                       ln_p_w, ln_p_b, W_pb, b_pb, W_pg, b_pg,
                       qs, ksf, vtb, pnum, pden);
    hipLaunchKernelGGL(reduce_out_kernel, dim3(NI / 2), dim3(256), 0, stream,
                       pnum, pden, gs, qx, Wo, bo, nmask, outp);
}

// Round 7
// 108.895 us; speedup vs baseline: 2.0190x; 2.0190x over previous
//
#include <hip/hip_runtime.h>
#include <hip/hip_bf16.h>

#define NI 768
#define NJ 768
#define CN 512
#define CP 128
#define NH 8
#define CH 32
#define HC 256   // NH*CH

typedef float  fx4  __attribute__((ext_vector_type(4)));
typedef float  fx2  __attribute__((ext_vector_type(2)));
typedef short  bv8  __attribute__((ext_vector_type(8)));
typedef unsigned short usx4 __attribute__((ext_vector_type(4)));

__device__ __forceinline__ short f2bf(float f) {
    __hip_bfloat16 h = __float2bfloat16(f);
    return *reinterpret_cast<short*>(&h);
}
__device__ __forceinline__ float bf2f(unsigned short u) {
    union { unsigned int u; float f; } c; c.u = ((unsigned int)u) << 16; return c.f;
}

// ---------------------------------------------------------------- fused front
// blocks [0,96):   i-side: LN(node_i) -> qx(f32), qsb(bf16 scaled), gs(f32)
// blocks [96,192): j-side: LN(node_j) -> ksb(bf16), vtb(bf16 transposed [HC][NJ])
// blocks [192,9408): pair-bias, one i x 64 j per block. LN stats via MFMA:
//   sum  = mfma(A, ones)  (row-sums, land in-lane)
//   ssq  = diag of mfma(A, A) (Gram), one shuffle
// Bias staged in LDS, written bf16 coalesced. Pair loads hoisted before the
// in-LDS weight rebuild to hide HBM latency.
__global__ __launch_bounds__(256) void fused_front_kernel(
    const float* __restrict__ node_i, const float* __restrict__ node_j,
    const float* __restrict__ ln_i_w, const float* __restrict__ ln_i_b,
    const float* __restrict__ ln_j_w, const float* __restrict__ ln_j_b,
    const float* __restrict__ Wq, const float* __restrict__ Wk,
    const float* __restrict__ Wv, const float* __restrict__ Wg,
    const float* __restrict__ bg,
    const float* __restrict__ lnpw, const float* __restrict__ lnpb,
    const float* __restrict__ Wpb, const float* __restrict__ bpb,
    const float* __restrict__ Wpg, const float* __restrict__ bpg,
    const float* __restrict__ pair, const float* __restrict__ pmask,
    float* __restrict__ qx, unsigned short* __restrict__ qsb,
    unsigned short* __restrict__ ksb, unsigned short* __restrict__ vtb,
    float* __restrict__ gs, unsigned short* __restrict__ biasb)
{
    const int bid = blockIdx.x;
    const int t = threadIdx.x;
    if (bid < 192) {
        __shared__ float xs[8][CN];
        __shared__ float red[4][8][2];
        const bool isj = bid >= 96;
        const int r0 = (isj ? bid - 96 : bid) * 8;
        const float* xin = isj ? node_j : node_i;
        const float* lw = isj ? ln_j_w : ln_i_w;
        const float* lb = isj ? ln_j_b : ln_i_b;
        const int wv = t >> 6;

        fx2 vrow[8]; float s8[8], q8[8];
#pragma unroll
        for (int r = 0; r < 8; ++r) {
            vrow[r] = *(const fx2*)(xin + (size_t)(r0 + r) * CN + t * 2);
            s8[r] = vrow[r][0] + vrow[r][1];
            q8[r] = vrow[r][0] * vrow[r][0] + vrow[r][1] * vrow[r][1];
        }
#pragma unroll
        for (int d = 1; d < 64; d <<= 1)
#pragma unroll
            for (int r = 0; r < 8; ++r) {
                s8[r] += __shfl_xor(s8[r], d);
                q8[r] += __shfl_xor(q8[r], d);
            }
        if ((t & 63) == 0)
#pragma unroll
            for (int r = 0; r < 8; ++r) { red[wv][r][0] = s8[r]; red[wv][r][1] = q8[r]; }
        __syncthreads();
        fx2 lwv = *(const fx2*)(lw + t * 2), lbv = *(const fx2*)(lb + t * 2);
#pragma unroll
        for (int r = 0; r < 8; ++r) {
            float s = red[0][r][0] + red[1][r][0] + red[2][r][0] + red[3][r][0];
            float q = red[0][r][1] + red[1][r][1] + red[2][r][1] + red[3][r][1];
            float mean = s * (1.f / CN);
            float var = q * (1.f / CN) - mean * mean;
            float rs = rsqrtf(var + 1e-5f);
            fx2 o;
            o[0] = (vrow[r][0] - mean) * rs * lwv[0] + lbv[0];
            o[1] = (vrow[r][1] - mean) * rs * lwv[1] + lbv[1];
            xs[r][t * 2] = o[0]; xs[r][t * 2 + 1] = o[1];
            if (!isj) *(fx2*)(qx + (size_t)(r0 + r) * CN + t * 2) = o;
        }
        __syncthreads();

        for (int m = 0; m < 2; ++m) {
            const float* W = isj ? (m ? Wv : Wk) : (m ? Wg : Wq);
            float acc[8] = {0.f,0.f,0.f,0.f,0.f,0.f,0.f,0.f};
            for (int cc = 0; cc < CN; cc += 4) {
                fx4 xv[8];
#pragma unroll
                for (int r = 0; r < 8; ++r) xv[r] = *(const fx4*)&xs[r][cc];
#pragma unroll
                for (int u = 0; u < 4; ++u) {
                    float w = W[(size_t)(cc + u) * HC + t];
#pragma unroll
                    for (int r = 0; r < 8; ++r) acc[r] = fmaf(xv[r][u], w, acc[r]);
                }
            }
            if (!isj) {
                if (m == 0) {
#pragma unroll
                    for (int r = 0; r < 8; ++r)
                        qsb[(size_t)(r0 + r) * HC + t] =
                            (unsigned short)f2bf(acc[r] * 0.17677669529663687f);
                } else {
#pragma unroll
                    for (int r = 0; r < 8; ++r)
                        gs[(size_t)(r0 + r) * HC + t] =
                            1.f / (1.f + __expf(-(acc[r] + bg[t])));
                }
            } else {
                if (m == 0) {
#pragma unroll
                    for (int r = 0; r < 8; ++r)
                        ksb[(size_t)(r0 + r) * HC + t] = (unsigned short)f2bf(acc[r]);
                } else {
                    bv8 vv;
#pragma unroll
                    for (int r = 0; r < 8; ++r) vv[r] = f2bf(acc[r]);
                    *(bv8*)&vtb[(size_t)t * NJ + r0] = vv;   // transposed [HC][NJ]
                }
            }
        }
        return;
    }

    // ---- pair path: one i, 64 consecutive j per block ----
    __shared__ unsigned short wcatT[16][136];
    __shared__ float redS[16][16], redC[16][16];
    __shared__ float scalS[16], scalC[16];
    __shared__ unsigned short sb[8][68];

    const int lane = t & 63;
    const int wave = t >> 6;
    const int bid2 = bid - 192;
    const int i    = bid2 / 12;
    const int jt64 = (bid2 % 12) * 64;
    const int jt   = jt64 + wave * 16;
    const int o  = lane & 15;
    const int kq = lane >> 4;

    // ---- early pair loads (HBM stream in flight before rebuild) ----
    const float* prow = pair + ((size_t)i * NJ + (jt + o)) * CP + kq * 8;
    fx4 x0[4], x1[4];
#pragma unroll
    for (int s = 0; s < 4; ++s) {
        x0[s] = *(const fx4*)(prow + s * 32);
        x1[s] = *(const fx4*)(prow + s * 32 + 4);
    }

    // ---- weight rebuild in LDS (covers load latency) ----
    {
        const int oo = t & 15, cg = t >> 4;
        float pS = 0.f, pC = 0.f;
#pragma unroll
        for (int e = 0; e < 8; ++e) {
            int c = cg * 8 + e;
            float w = (oo < 8) ? Wpb[c * 8 + oo] : Wpg[c * 8 + (oo - 8)];
            float wv = lnpw[c] * w;
            short b = f2bf(wv);
            wcatT[oo][c] = (unsigned short)b;
            pS += bf2f((unsigned short)b);
            pC += lnpb[c] * w;
        }
        redS[cg][oo] = pS; redC[cg][oo] = pC;
        __syncthreads();
        if (t < 16) {
            float s = 0.f, c2 = 0.f;
#pragma unroll
            for (int k = 0; k < 16; ++k) { s += redS[k][t]; c2 += redC[k][t]; }
            scalS[t] = s;
            scalC[t] = c2 + ((t < 8) ? bpb[t] : bpg[t - 8]);
        }
        __syncthreads();
    }

    bv8 bfrag[4];
#pragma unroll
    for (int s = 0; s < 4; ++s)
        bfrag[s] = *(const bv8*)&wcatT[o][s * 32 + kq * 8];
    const float spb = scalS[o];
    const float cpb = scalC[o];

    // A fragments (bf16), stats via MFMA (no scalar stats FMAs)
    bv8 afrag[4];
#pragma unroll
    for (int s = 0; s < 4; ++s) {
#pragma unroll
        for (int u = 0; u < 4; ++u) {
            afrag[s][u]     = f2bf(x0[s][u]);
            afrag[s][u + 4] = f2bf(x1[s][u]);
        }
    }
    bv8 ones;
#pragma unroll
    for (int u = 0; u < 8; ++u) ones[u] = (short)0x3F80;   // bf16 1.0

    fx4 acc  = {0.f, 0.f, 0.f, 0.f};   // projection
    fx4 accS = {0.f, 0.f, 0.f, 0.f};   // row sums   (A * ones)
    fx4 accG = {0.f, 0.f, 0.f, 0.f};   // Gram diag  (A * A^T)
#pragma unroll
    for (int s = 0; s < 4; ++s) {
        acc  = __builtin_amdgcn_mfma_f32_16x16x32_bf16(afrag[s], bfrag[s], acc,  0, 0, 0);
        accS = __builtin_amdgcn_mfma_f32_16x16x32_bf16(afrag[s], ones,     accS, 0, 0, 0);
        accG = __builtin_amdgcn_mfma_f32_16x16x32_bf16(afrag[s], afrag[s], accG, 0, 0, 0);
    }

#pragma unroll
    for (int r = 0; r < 4; ++r) {
        const int p = kq * 4 + r;
        // accS[r] = rowsum[p] (in-lane: D row = kq*4+r). Gram diag at lane kq*20+r.
        float sp = accS[r];
        float qp = __shfl(accG[r], kq * 20 + r);
        float mean = sp * (1.f / CP);
        float var  = qp * (1.f / CP) - mean * mean;
        float rstd = rsqrtf(var + 1e-5f);
        float pre  = rstd * (acc[r] - mean * spb) + cpb;
        float part = __shfl_xor(pre, 8);
        if (o < 8) {
            float sig = 1.f / (1.f + __expf(-part));
            int j = jt + p;
            float b = pre * sig + (pmask[(size_t)i * NJ + j] - 1.f) * 1.0e9f;
            sb[o][wave * 16 + p] = (unsigned short)f2bf(b);
        }
    }
    __syncthreads();
    if (t < 128) {
        const int oo = t >> 4, ck = t & 15;
        usx4 v;
#pragma unroll
        for (int u = 0; u < 4; ++u) v[u] = sb[oo][ck * 4 + u];
        *(usx4*)&biasb[((size_t)oo * NI + i) * NJ + jt64 + ck * 4] = v;
    }
}

// ---------------------------------------------------------------- attention (MFMA, j-split)
// grid (24, 8, 2): (32-row i-tile, head, j-half). Partials pnum/pden.
__global__ __launch_bounds__(256) void attn_kernel(
    const short* __restrict__ qsb, const short* __restrict__ ksb,
    const short* __restrict__ vtb, const unsigned short* __restrict__ biasb,
    float* __restrict__ pnum, float* __restrict__ pden)
{
    __shared__ unsigned short P[32][392];
    __shared__ float sumbuf[4][32];
    const int i0 = blockIdx.x * 32;
    const int h  = blockIdx.y;
    const int jh = blockIdx.z;
    const int jbase = jh * 384;
    const int pb = ((int)blockIdx.x * NH + h) * 2 + jh;
    const int t = threadIdx.x;
    const int w = t >> 6;
    const int lane = t & 63;
    const int rowl = lane & 15;
    const int g = lane >> 4;

    bv8 aq[2];
#pragma unroll
    for (int it = 0; it < 2; ++it)
        aq[it] = *(const bv8*)&qsb[(size_t)(i0 + it * 16 + rowl) * HC + h * CH + g * 8];

    const unsigned short* bbase = biasb + (size_t)h * NI * NJ;
    float rs[2][4] = {{0.f,0.f,0.f,0.f},{0.f,0.f,0.f,0.f}};
    for (int jt = 0; jt < 6; ++jt) {
        const int jloc = w * 96 + jt * 16;
        const int jb = jbase + jloc;
        bv8 bk = *(const bv8*)&ksb[(size_t)(jb + rowl) * HC + h * CH + g * 8];
#pragma unroll
        for (int it = 0; it < 2; ++it) {
            fx4 acc = {0.f, 0.f, 0.f, 0.f};
            acc = __builtin_amdgcn_mfma_f32_16x16x32_bf16(aq[it], bk, acc, 0, 0, 0);
#pragma unroll
            for (int r = 0; r < 4; ++r) {
                const int il = it * 16 + g * 4 + r;
                float s = acc[r] + bf2f(bbase[(size_t)(i0 + il) * NJ + jb + rowl]);
                float p = __expf(s);
                rs[it][r] += p;
                P[il][jloc + rowl] = (unsigned short)f2bf(p);
            }
        }
    }
#pragma unroll
    for (int it = 0; it < 2; ++it)
#pragma unroll
        for (int r = 0; r < 4; ++r) {
            float v = rs[it][r];
            v += __shfl_xor(v, 1); v += __shfl_xor(v, 2);
            v += __shfl_xor(v, 4); v += __shfl_xor(v, 8);
            rs[it][r] = v;
        }
    if (rowl == 0) {
#pragma unroll
        for (int it = 0; it < 2; ++it)
#pragma unroll
            for (int r = 0; r < 4; ++r)
                sumbuf[w][it * 16 + g * 4 + r] = rs[it][r];
    }
    __syncthreads();

    if (t < 32)
        pden[(size_t)pb * 32 + t] =
            sumbuf[0][t] + sumbuf[1][t] + sumbuf[2][t] + sumbuf[3][t];

    const int it = w & 1, ct = w >> 1;
    fx4 acc = {0.f, 0.f, 0.f, 0.f};
    for (int kk = 0; kk < 12; ++kk) {
        const int jloc = kk * 32;
        bv8 ap = *(const bv8*)&P[it * 16 + rowl][jloc + g * 8];
        bv8 bv = *(const bv8*)&vtb[(size_t)(h * CH + ct * 16 + rowl) * NJ + jbase + jloc + g * 8];
        acc = __builtin_amdgcn_mfma_f32_16x16x32_bf16(ap, bv, acc, 0, 0, 0);
    }
#pragma unroll
    for (int r = 0; r < 4; ++r) {
        const int il = it * 16 + g * 4 + r;
        pnum[(size_t)pb * 1024 + il * 32 + ct * 16 + rowl] = acc[r];
    }
}

// ---------------------------------------------------------------- combine + gate + out-proj + residual
__global__ __launch_bounds__(256) void combine_out_kernel(
    const float* __restrict__ pnum, const float* __restrict__ pden,
    const float* __restrict__ gs, const float* __restrict__ qx,
    const float* __restrict__ Wo, const float* __restrict__ bo,
    const float* __restrict__ mi, float* __restrict__ outp)
{
    __shared__ float ogl[2][HC];
    const int r0 = blockIdx.x * 2;
    const int t = threadIdx.x;
    const int h = t >> 5, c = t & 31;
#pragma unroll
    for (int r = 0; r < 2; ++r) {
        const int i = r0 + r;
        const int pb = ((i >> 5) * NH + h) * 2;
        const int il = i & 31;
        float n = pnum[(size_t)(pb + 0) * 1024 + il * 32 + c]
                + pnum[(size_t)(pb + 1) * 1024 + il * 32 + c];
        float d = pden[(size_t)(pb + 0) * 32 + il]
                + pden[(size_t)(pb + 1) * 32 + il];
        ogl[r][t] = n / d * gs[(size_t)i * HC + t];
    }
    __syncthreads();

    float acc[2][2] = {{0,0},{0,0}};
    for (int cc = 0; cc < HC; cc += 4) {
        fx4 xr0 = *(const fx4*)&ogl[0][cc];
        fx4 xr1 = *(const fx4*)&ogl[1][cc];
#pragma unroll
        for (int u = 0; u < 4; ++u) {
            float w0 = Wo[(size_t)(cc + u) * CN + t];
            float w1 = Wo[(size_t)(cc + u) * CN + 256 + t];
            acc[0][0] = fmaf(xr0[u], w0, acc[0][0]); acc[0][1] = fmaf(xr0[u], w1, acc[0][1]);
            acc[1][0] = fmaf(xr1[u], w0, acc[1][0]); acc[1][1] = fmaf(xr1[u], w1, acc[1][1]);
        }
    }
#pragma unroll
    for (int r = 0; r < 2; ++r) {
        float mk = mi[r0 + r];
        size_t base = (size_t)(r0 + r) * CN;
        outp[base + t]       = qx[base + t]       + (acc[r][0] + bo[t])       * mk;
        outp[base + 256 + t] = qx[base + 256 + t] + (acc[r][1] + bo[t + 256]) * mk;
    }
}

// ---------------------------------------------------------------- launch
extern "C" void kernel_launch(void* const* d_in, const int* in_sizes, int n_in,
                              void* d_out, int out_size, void* d_ws, size_t ws_size,
                              hipStream_t stream)
{
    const float* node_i = (const float*)d_in[0];
    const float* node_j = (const float*)d_in[1];
    const float* pair   = (const float*)d_in[2];
    const float* pmask  = (const float*)d_in[3];
    const float* nmask  = (const float*)d_in[4];
    const float* ln_i_w = (const float*)d_in[5];
    const float* ln_i_b = (const float*)d_in[6];
    const float* ln_j_w = (const float*)d_in[7];
    const float* ln_j_b = (const float*)d_in[8];
    const float* ln_p_w = (const float*)d_in[9];
    const float* ln_p_b = (const float*)d_in[10];
    const float* W_pb   = (const float*)d_in[11];
    const float* b_pb   = (const float*)d_in[12];
    const float* W_pg   = (const float*)d_in[13];
    const float* b_pg   = (const float*)d_in[14];
    const float* Wq     = (const float*)d_in[15];
    const float* Wk     = (const float*)d_in[16];
    const float* Wv     = (const float*)d_in[17];
    const float* Wg     = (const float*)d_in[18];
    const float* bg     = (const float*)d_in[19];
    const float* Wo     = (const float*)d_in[20];
    const float* bo     = (const float*)d_in[21];
    float* outp = (float*)d_out;

    float* fw = (float*)d_ws;
    float* qx   = fw;                              // [NI][CN]
    float* gs   = qx + (size_t)NI * CN;            // [NI][HC]
    float* pnum = gs + (size_t)NI * HC;            // [24*8*2][1024]
    float* pden = pnum + (size_t)24 * NH * 2 * 1024; // [24*8*2][32]
    unsigned short* qsb = (unsigned short*)(pden + (size_t)24 * NH * 2 * 32); // [NI][HC]
    unsigned short* ksb = qsb + (size_t)NI * HC;    // [NJ][HC]
    unsigned short* vtb = ksb + (size_t)NJ * HC;    // [HC][NJ]
    unsigned short* biasb = vtb + (size_t)HC * NJ;  // [NH][NI][NJ] bf16

    hipLaunchKernelGGL(fused_front_kernel, dim3(192 + (NI * NJ) / 64), dim3(256), 0, stream,
                       node_i, node_j, ln_i_w, ln_i_b, ln_j_w, ln_j_b,
                       Wq, Wk, Wv, Wg, bg,
                       ln_p_w, ln_p_b, W_pb, b_pb, W_pg, b_pg,
                       pair, pmask,
                       qx, qsb, ksb, vtb, gs, biasb);
    hipLaunchKernelGGL(attn_kernel, dim3(NI / 32, NH, 2), dim3(256), 0, stream,
                       (const short*)qsb, (const short*)ksb, (const short*)vtb,
                       biasb, pnum, pden);
    hipLaunchKernelGGL(combine_out_kernel, dim3(NI / 2), dim3(256), 0, stream,
                       pnum, pden, gs, qx, Wo, bo, nmask, outp);
}